// Round 9
// baseline (386.721 us; speedup 1.0000x reference)
//
#include <hip/hip_runtime.h>
#include <hip/hip_bf16.h>
#include <math.h>

#define WINDOW 1024

typedef __bf16 bf16;
typedef __bf16 bf16x8 __attribute__((ext_vector_type(8)));
typedef __bf16 bf16x4 __attribute__((ext_vector_type(4)));
typedef float floatx4 __attribute__((ext_vector_type(4)));

static __device__ __forceinline__ bf16x8 load_bf8(const bf16* p) {
    return *reinterpret_cast<const bf16x8*>(p);
}

// async 16B global->LDS (wave-uniform LDS base + lane*16)
static __device__ __forceinline__ void async16(const bf16* g, bf16* l) {
    __builtin_amdgcn_global_load_lds(
        (const __attribute__((address_space(1))) void*)g,
        (__attribute__((address_space(3))) void*)l, 16, 0, 0);
}

// Manual grid barrier. Sound because: __launch_bounds__(256,1) + 96KB static
// LDS => exactly 1 block/CU; grid = 256 = CU count => all blocks co-resident
// (guide §1 capacity formula). Release: per-thread threadfence flushes writes
// to the device-coherent point. Arrival/poll via device-scope atomic RMW
// (a plain load could spin on a stale per-XCD L2 line forever). Acquire:
// threadfence after release invalidates stale L2/L1 before cross-XCD reads.
// Counters are memset to 0 before each launch (graph-capturable).
static __device__ __forceinline__ void gridbar(unsigned* ctr) {
    __threadfence();                  // release this thread's writes
    __syncthreads();                  // whole block arrived & released
    if (threadIdx.x == 0) {
        atomicAdd(ctr, 1u);
        while (atomicAdd(ctr, 0u) < 256u) __builtin_amdgcn_s_sleep(8);
    }
    __syncthreads();                  // block-wide release from the spin
    __threadfence();                  // acquire: invalidate stale caches
}

// ===========================================================================
// ONE kernel: convert -> qkv(+clip/RMS/RoPE) -> attn -> out-proj.
// r7 accounting: per-dispatch ceilings (all <=47us) sum to ~145-160us yet wall
// = 206us; r2's total regression exceeded component deltas by ~12us. Theory:
// ~40-60us lives BETWEEN dispatches (launch/drain boundaries + DVFS re-ramp;
// effective clock ~1GHz inferred from MfmaUtil arithmetic). Fusion removes 3
// boundaries. r8's cooperative-launch attempt failed ambiguously (infra vs
// coop-in-capture); this round uses a manual co-residency barrier instead.
// Phase bodies = proven r3/r6 variants, byte-identical numerics.
// ===========================================================================
__global__ __launch_bounds__(256, 1) void fused_all(
    const float* __restrict__ x, const float* __restrict__ wq,
    const float* __restrict__ wk, const float* __restrict__ wv,
    const float* __restrict__ wo, const float* __restrict__ qnw,
    const float* __restrict__ knw, const float* __restrict__ sinks,
    bf16* __restrict__ xb, bf16* __restrict__ wqb, bf16* __restrict__ wkb,
    bf16* __restrict__ wvb, bf16* __restrict__ wob, bf16* __restrict__ qb,
    bf16* __restrict__ kb, bf16* __restrict__ vtb, bf16* __restrict__ attb,
    float* __restrict__ out, unsigned* __restrict__ bar) {
    __shared__ __align__(16) char sraw[98304];  // 96 KB union for all phases
    int bid = blockIdx.x;
    int tid = threadIdx.x;
    int lane = tid & 63, wid = tid >> 6;
    int l15 = lane & 15, quad = lane >> 4;

    // ---------------- phase 0: fp32 -> bf16 conversion ----------------
    for (int i = bid * 256 + tid; i < 3670016; i += 256 * 256) {
        const float* src; bf16* dst; int off;
        if      (i < 1048576) { src = x;  dst = xb;  off = i; }
        else if (i < 2097152) { src = wq; dst = wqb; off = i - 1048576; }
        else if (i < 2359296) { src = wk; dst = wkb; off = i - 2097152; }
        else if (i < 2621440) { src = wv; dst = wvb; off = i - 2359296; }
        else                  { src = wo; dst = wob; off = i - 2621440; }
        float4 v = reinterpret_cast<const float4*>(src)[off];
        union { bf16 b[4]; ushort4 u; } t;
        t.b[0] = (bf16)v.x; t.b[1] = (bf16)v.y;
        t.b[2] = (bf16)v.z; t.b[3] = (bf16)v.w;
        reinterpret_cast<ushort4*>(dst)[off] = t.u;
    }
    gridbar(bar + 0);

    // ------- phase 1: QKV GEMM + clip + RMSNorm + RoPE (r3 fat-wave) -------
    // blocks 0..191 active; 192..255 go straight to the grid barrier.
    if (bid < 192) {
        const int K = 2048;
        int xcd = bid & 7, w = bid >> 3;            // w in 0..23
        int mrow = xcd * 2 + (w >= 12);
        int ncol = (w >= 12) ? (w - 12) : w;
        int m0 = mrow * 128, n0 = ncol * 256;
        bf16* smem = (bf16*)sraw;                   // 2 x 24576 bf16 = 96 KB
        const bf16* Bw = wqb;                       // wcomb [3072][2048]
        int rlocal = lane >> 3;
        int scol = ((lane & 7) ^ rlocal) * 8;
        const bf16* gA = xb + (size_t)(m0 + wid * 32 + rlocal) * K + scol;
        const bf16* gB = Bw + (size_t)(n0 + wid * 64 + rlocal) * K + scol;
        int mb = (wid & 1) * 64, nb = (wid >> 1) * 128;

        floatx4 acc[4][8];
#pragma unroll
        for (int mi = 0; mi < 4; ++mi)
#pragma unroll
            for (int ni = 0; ni < 8; ++ni)
                acc[mi][ni] = floatx4{0.f, 0.f, 0.f, 0.f};

        // prologue: stage k-tile 0 into buf 0
#pragma unroll
        for (int j = 0; j < 4; ++j)
            async16(gA + (size_t)(j * 8) * K, smem + (wid * 32 + j * 8) * 64);
#pragma unroll
        for (int j = 0; j < 8; ++j)
            async16(gB + (size_t)(j * 8) * K,
                    smem + 8192 + (wid * 64 + j * 8) * 64);

        int buf = 0;
        for (int k0 = 0; k0 < K; k0 += 64) {
            __syncthreads();
            if (k0 + 64 < K) {
                bf16* nbase = smem + (buf ^ 1) * 24576;
#pragma unroll
                for (int j = 0; j < 4; ++j)
                    async16(gA + (size_t)(j * 8) * K + k0 + 64,
                            nbase + (wid * 32 + j * 8) * 64);
#pragma unroll
                for (int j = 0; j < 8; ++j)
                    async16(gB + (size_t)(j * 8) * K + k0 + 64,
                            nbase + 8192 + (wid * 64 + j * 8) * 64);
            }
            const bf16* sA = smem + buf * 24576;
            const bf16* sB = sA + 8192;
#pragma unroll
            for (int kc = 0; kc < 2; ++kc) {
                bf16x8 af[4], bq[8];
                int ch = ((kc << 2) + quad) ^ (l15 & 7);
#pragma unroll
                for (int i = 0; i < 4; ++i)
                    af[i] = load_bf8(sA + (mb + i * 16 + l15) * 64 + ch * 8);
#pragma unroll
                for (int n = 0; n < 8; ++n)
                    bq[n] = load_bf8(sB + (nb + n * 16 + l15) * 64 + ch * 8);
#pragma unroll
                for (int mi = 0; mi < 4; ++mi)
#pragma unroll
                    for (int ni = 0; ni < 8; ++ni)
                        acc[mi][ni] = __builtin_amdgcn_mfma_f32_16x16x32_bf16(
                            af[mi], bq[ni], acc[mi][ni], 0, 0, 0);
            }
            buf ^= 1;
        }

        // clip
#pragma unroll
        for (int mi = 0; mi < 4; ++mi)
#pragma unroll
            for (int ni = 0; ni < 8; ++ni)
#pragma unroll
                for (int r = 0; r < 4; ++r)
                    acc[mi][ni][r] = fminf(fmaxf(acc[mi][ni][r], -8.0f), 8.0f);

        if (n0 >= 2560) {  // V: transpose-store (NO return — must reach bar)
#pragma unroll
            for (int mi = 0; mi < 4; ++mi)
#pragma unroll
                for (int ni = 0; ni < 8; ++ni)
#pragma unroll
                    for (int r = 0; r < 4; ++r) {
                        int row = m0 + mb + mi * 16 + quad * 4 + r;
                        int n = n0 + nb + ni * 16 + l15;
                        vtb[(size_t)(n - 2560) * 2048 + row] =
                            (bf16)acc[mi][ni][r];
                    }
        } else {
            // RMSNorm in-register (wave owns all 128 cols of its head)
            const float* nw = (n0 < 2048) ? qnw : knw;
            float nwv[8];
#pragma unroll
            for (int ni = 0; ni < 8; ++ni)
                nwv[ni] = nw[(nb + ni * 16 + l15) & 127];
#pragma unroll
            for (int mi = 0; mi < 4; ++mi)
#pragma unroll
                for (int r = 0; r < 4; ++r) {
                    float s = 0.f;
#pragma unroll
                    for (int ni = 0; ni < 8; ++ni)
                        s += acc[mi][ni][r] * acc[mi][ni][r];
#pragma unroll
                    for (int o = 1; o < 16; o <<= 1) s += __shfl_xor(s, o, 64);
                    float rinv = rsqrtf(s * (1.0f / 128.0f) + 1e-6f);
#pragma unroll
                    for (int ni = 0; ni < 8; ++ni)
                        acc[mi][ni][r] *= rinv * nwv[ni];
                }
            // RoPE (partner = ni^4, in-register) + store
            float invf[4];
#pragma unroll
            for (int ni = 0; ni < 4; ++ni) {
                int fi = ni * 16 + l15;
                invf[ni] = __expf((float)fi * (-13.122363377404328f / 64.0f));
            }
#pragma unroll
            for (int mi = 0; mi < 4; ++mi)
#pragma unroll
                for (int r = 0; r < 4; ++r) {
                    int row = mb + mi * 16 + quad * 4 + r;
                    int s = m0 + row;
                    float pos = (float)s;
#pragma unroll
                    for (int ni = 0; ni < 4; ++ni) {
                        float ang = pos * invf[ni];
                        float c = __cosf(ang), sn = __sinf(ang);
                        float a = acc[mi][ni][r], b2 = acc[mi][ni + 4][r];
                        float olo = a * c - b2 * sn;
                        float ohi = b2 * c + a * sn;
                        int nlo = n0 + nb + ni * 16 + l15;
                        if (n0 < 2048) {
                            qb[(size_t)s * 2048 + nlo] = (bf16)olo;
                            qb[(size_t)s * 2048 + nlo + 64] = (bf16)ohi;
                        } else {
                            kb[(size_t)s * 512 + (nlo - 2048)] = (bf16)olo;
                            kb[(size_t)s * 512 + (nlo - 2048) + 64] = (bf16)ohi;
                        }
                    }
                }
        }
    }
    gridbar(bar + 1);

    // ------- phase 2: flash attention (r6 4-wave), 2 units per block -------
    {
        bf16* sK0 = (bf16*)sraw;                    // 2 x 64*128
        bf16* sV0 = (bf16*)(sraw + 32768);          // 2 x 128*64
        bf16* sP  = (bf16*)(sraw + 65536);          // 64*72
        float (*redu)[4] = (float(*)[4])(sraw + 65536 + 9216);

        for (int u = 0; u < 2; ++u) {
            int unit = bid * 2 + u;                 // 0..511
            int xcd = unit & 7, w = unit >> 3;      // w in 0..63
            int h = xcd * 2 + (w >> 5);
            int kh = h >> 2;
            int bq0 = (w & 31) * 64;
            __syncthreads();  // prior unit's LDS fully consumed

            bf16x8 qf[4][4];
#pragma unroll
            for (int ni = 0; ni < 4; ++ni) {
                const bf16* qrow = qb + (size_t)(bq0 + ni * 16 + l15) * 2048 +
                                   h * 128 + quad * 8;
#pragma unroll
                for (int kc = 0; kc < 4; ++kc)
                    qf[ni][kc] = load_bf8(qrow + kc * 32);
            }

            floatx4 acc[4][2];
#pragma unroll
            for (int mi = 0; mi < 4; ++mi)
#pragma unroll
                for (int df = 0; df < 2; ++df)
                    acc[mi][df] = floatx4{0.f, 0.f, 0.f, 0.f};
            float lpq[4];
#pragma unroll
            for (int ni = 0; ni < 4; ++ni) lpq[ni] = 0.f;

            int keyit = wid * 4 + (lane >> 4);
            int gcK = (lane & 15) ^ keyit;
            int dimit = wid * 8 + (lane >> 3);
            int gcV = (lane & 7) ^ ((lane >> 3) & 7);

            int tstart = bq0 - 1024; if (tstart < 0) tstart = 0;
            const bf16* kbase = kb + (size_t)kh * 128;
            const bf16* vbase = vtb + (size_t)kh * 128 * 2048;

#pragma unroll
            for (int r = 0; r < 4; ++r) {
                async16(kbase + (size_t)(tstart + r * 16 + keyit) * 512 + gcK * 8,
                        sK0 + (r * 16 + wid * 4) * 128);
                async16(vbase + (size_t)(r * 32 + dimit) * 2048 + tstart + gcV * 8,
                        sV0 + (r * 32 + wid * 8) * 64);
            }

            int buf = 0;
            for (int t = tstart; t <= bq0; t += 64) {
                __syncthreads();
                if (t + 64 <= bq0) {
#pragma unroll
                    for (int r = 0; r < 4; ++r) {
                        async16(kbase + (size_t)(t + 64 + r * 16 + keyit) * 512 + gcK * 8,
                                sK0 + (buf ^ 1) * 8192 + (r * 16 + wid * 4) * 128);
                        async16(vbase + (size_t)(r * 32 + dimit) * 2048 + t + 64 + gcV * 8,
                                sV0 + (buf ^ 1) * 8192 + (r * 32 + wid * 8) * 64);
                    }
                }
                // phase A: S^T = K.Q^T for this wave's 16 keys
                floatx4 ST[4];
#pragma unroll
                for (int ni = 0; ni < 4; ++ni)
                    ST[ni] = floatx4{0.f, 0.f, 0.f, 0.f};
#pragma unroll
                for (int kc = 0; kc < 4; ++kc) {
                    int ch = (kc * 4 + quad) ^ l15;
                    bf16x8 kf = load_bf8(sK0 + buf * 8192 +
                                         (wid * 16 + l15) * 128 + ch * 8);
#pragma unroll
                    for (int ni = 0; ni < 4; ++ni)
                        ST[ni] = __builtin_amdgcn_mfma_f32_16x16x32_bf16(
                            kf, qf[ni][kc], ST[ni], 0, 0, 0);
                }
                int kbi = t + wid * 16 + quad * 4;
#pragma unroll
                for (int ni = 0; ni < 4; ++ni) {
                    int qi = bq0 + ni * 16 + l15;
                    bf16x4 pv;
#pragma unroll
                    for (int r = 0; r < 4; ++r) {
                        int ki = kbi + r;
                        float v = ST[ni][r] * 0.08838834764831845f;
                        bool ok = (ki <= qi) && (ki > qi - WINDOW);
                        float e = ok ? __expf(v) : 0.0f;
                        lpq[ni] += e;
                        pv[r] = (bf16)e;
                    }
                    *(bf16x4*)(sP + (ni * 16 + l15) * 72 + wid * 16 + quad * 4) = pv;
                }
                __syncthreads();
                // phase B: PV for this wave's 32 dims
#pragma unroll
                for (int kc = 0; kc < 2; ++kc) {
                    bf16x8 pf[4];
#pragma unroll
                    for (int mi = 0; mi < 4; ++mi)
                        pf[mi] = load_bf8(sP + (mi * 16 + l15) * 72 +
                                          kc * 32 + quad * 8);
#pragma unroll
                    for (int df = 0; df < 2; ++df) {
                        int dim = wid * 32 + df * 16 + l15;
                        int ch = (kc * 4 + quad) ^ (l15 & 7);
                        bf16x8 vf = load_bf8(sV0 + buf * 8192 + dim * 64 + ch * 8);
#pragma unroll
                        for (int mi = 0; mi < 4; ++mi)
                            acc[mi][df] = __builtin_amdgcn_mfma_f32_16x16x32_bf16(
                                pf[mi], vf, acc[mi][df], 0, 0, 0);
                    }
                }
                buf ^= 1;
            }

#pragma unroll
            for (int ni = 0; ni < 4; ++ni) {
                float v = lpq[ni];
                v += __shfl_xor(v, 16, 64);
                v += __shfl_xor(v, 32, 64);
                if (quad == 0) redu[ni * 16 + l15][wid] = v;
            }
            __syncthreads();
            float sk = __expf(sinks[h]);
#pragma unroll
            for (int mi = 0; mi < 4; ++mi)
#pragma unroll
                for (int r = 0; r < 4; ++r) {
                    int row = mi * 16 + quad * 4 + r;
                    float rs = redu[row][0] + redu[row][1] + redu[row][2] +
                               redu[row][3] + sk;
                    float inv = 1.0f / rs;
#pragma unroll
                    for (int df = 0; df < 2; ++df) {
                        int dim = wid * 32 + df * 16 + l15;
                        attb[(size_t)(bq0 + row) * 2048 + h * 128 + dim] =
                            (bf16)(acc[mi][df][r] * inv);
                    }
                }
        }
    }
    gridbar(bar + 2);

    // ------- phase 3: out-proj GEMM (fat 128x128, depth-1 dbuf) -------
    {
        const int K = 2048, N = 2048;
        int xcd = bid & 7, w = bid >> 3;            // w in 0..31
        int m0 = (xcd * 2 + (w >> 4)) * 128;
        int n0 = (w & 15) * 128;
        bf16* smem = (bf16*)sraw;                   // 2 x 16384 bf16 = 64 KB
        int rlocal = lane >> 3;
        int scol = ((lane & 7) ^ rlocal) * 8;
        const bf16* gA = attb + (size_t)(m0 + wid * 32 + rlocal) * K + scol;
        const bf16* gB = wob + (size_t)(n0 + wid * 32 + rlocal) * K + scol;
        int mb = (wid & 1) * 64, nb = (wid >> 1) * 64;

        floatx4 acc[4][4];
#pragma unroll
        for (int mi = 0; mi < 4; ++mi)
#pragma unroll
            for (int ni = 0; ni < 4; ++ni)
                acc[mi][ni] = floatx4{0.f, 0.f, 0.f, 0.f};

#pragma unroll
        for (int j = 0; j < 4; ++j) {
            async16(gA + (size_t)(j * 8) * K, smem + (wid * 32 + j * 8) * 64);
            async16(gB + (size_t)(j * 8) * K,
                    smem + 8192 + (wid * 32 + j * 8) * 64);
        }

        int buf = 0;
        for (int k0 = 0; k0 < K; k0 += 64) {
            __syncthreads();
            if (k0 + 64 < K) {
                bf16* nbase = smem + (buf ^ 1) * 16384;
#pragma unroll
                for (int j = 0; j < 4; ++j) {
                    async16(gA + (size_t)(j * 8) * K + k0 + 64,
                            nbase + (wid * 32 + j * 8) * 64);
                    async16(gB + (size_t)(j * 8) * K + k0 + 64,
                            nbase + 8192 + (wid * 32 + j * 8) * 64);
                }
            }
            const bf16* sA = smem + buf * 16384;
            const bf16* sB = sA + 8192;
#pragma unroll
            for (int kc = 0; kc < 2; ++kc) {
                bf16x8 af[4], bq[4];
                int ch = ((kc << 2) + quad) ^ (l15 & 7);
#pragma unroll
                for (int i = 0; i < 4; ++i)
                    af[i] = load_bf8(sA + (mb + i * 16 + l15) * 64 + ch * 8);
#pragma unroll
                for (int n = 0; n < 4; ++n)
                    bq[n] = load_bf8(sB + (nb + n * 16 + l15) * 64 + ch * 8);
#pragma unroll
                for (int mi = 0; mi < 4; ++mi)
#pragma unroll
                    for (int ni = 0; ni < 4; ++ni)
                        acc[mi][ni] = __builtin_amdgcn_mfma_f32_16x16x32_bf16(
                            af[mi], bq[ni], acc[mi][ni], 0, 0, 0);
            }
            buf ^= 1;
        }

#pragma unroll
        for (int mi = 0; mi < 4; ++mi)
#pragma unroll
            for (int ni = 0; ni < 4; ++ni)
#pragma unroll
                for (int r = 0; r < 4; ++r) {
                    int m = m0 + mb + mi * 16 + quad * 4 + r;
                    int n = n0 + nb + ni * 16 + l15;
                    out[(size_t)m * N + n] = acc[mi][ni][r];
                }
    }
}

extern "C" void kernel_launch(void* const* d_in, const int* in_sizes, int n_in,
                              void* d_out, int out_size, void* d_ws, size_t ws_size,
                              hipStream_t stream) {
    const float* x      = (const float*)d_in[0];
    const float* w_q    = (const float*)d_in[1];
    const float* w_k    = (const float*)d_in[2];
    const float* w_v    = (const float*)d_in[3];
    const float* w_out  = (const float*)d_in[4];
    const float* q_norm = (const float*)d_in[5];
    const float* k_norm = (const float*)d_in[6];
    const float* sinks  = (const float*)d_in[7];

    char* ws = (char*)d_ws;
    const size_t MB = 1u << 20;
    bf16* xb   = (bf16*)(ws + 0 * MB);    // 8 MB
    bf16* wqb  = (bf16*)(ws + 8 * MB);    // 8 MB  (wqb/wkb/wvb contiguous)
    bf16* wkb  = (bf16*)(ws + 16 * MB);   // 2 MB  (forms wcomb [3072][2048])
    bf16* wvb  = (bf16*)(ws + 18 * MB);   // 2 MB
    bf16* wob  = (bf16*)(ws + 20 * MB);   // 8 MB
    bf16* qb   = (bf16*)(ws + 28 * MB);   // 8 MB  (post norm+rope)
    bf16* kb   = (bf16*)(ws + 36 * MB);   // 2 MB
    bf16* vtb  = (bf16*)(ws + 38 * MB);   // 2 MB  (V transposed)
    bf16* attb = (bf16*)(ws + 40 * MB);   // 8 MB
    unsigned* bar = (unsigned*)(ws + 48 * MB);  // 3 barrier counters
    float* out = (float*)d_out;

    hipMemsetAsync(bar, 0, 16, stream);
    fused_all<<<256, 256, 0, stream>>>(
        x, w_q, w_k, w_v, w_out, q_norm, k_norm, sinks,
        xb, wqb, wkb, wvb, wob, qb, kb, vtb, attb, out, bar);
}

// Round 10
// 200.247 us; speedup vs baseline: 1.9312x; 1.9312x over previous
//
#include <hip/hip_runtime.h>
#include <hip/hip_bf16.h>
#include <math.h>

#define S_LEN 2048
#define DMODEL 2048
#define NH 16
#define NKVH 4
#define HDIM 128
#define WINDOW 1024

typedef __bf16 bf16;
typedef __bf16 bf16x8 __attribute__((ext_vector_type(8)));
typedef __bf16 bf16x4 __attribute__((ext_vector_type(4)));
typedef float floatx4 __attribute__((ext_vector_type(4)));

static __device__ __forceinline__ bf16x8 load_bf8(const bf16* p) {
    return *reinterpret_cast<const bf16x8*>(p);
}

// async 16B global->LDS (wave-uniform LDS base + lane*16)
static __device__ __forceinline__ void async16(const bf16* g, bf16* l) {
    __builtin_amdgcn_global_load_lds(
        (const __attribute__((address_space(1))) void*)g,
        (__attribute__((address_space(3))) void*)l, 16, 0, 0);
}

// -------- fp32 -> bf16 conversion of x and QKV weights (wo moved to attn) ---
// r9 decomposition: wall = in-kernel sum (~146us) + FIXED ~56us harness
// overhead (measured: 1-dispatch fused kernel still showed wall-kernel=57us).
// So cut in-kernel streaming: wo conversion (29% of traffic) rides inside attn.
__global__ __launch_bounds__(256) void convert_kernel(
    const float* __restrict__ x, const float* __restrict__ wq,
    const float* __restrict__ wk, const float* __restrict__ wv,
    bf16* __restrict__ xb, bf16* __restrict__ wqb, bf16* __restrict__ wkb,
    bf16* __restrict__ wvb) {
    for (int i = blockIdx.x * blockDim.x + threadIdx.x; i < 2621440;
         i += gridDim.x * blockDim.x) {
        const float* src; bf16* dst; int off;
        if      (i < 1048576) { src = x;  dst = xb;  off = i; }
        else if (i < 2097152) { src = wq; dst = wqb; off = i - 1048576; }
        else if (i < 2359296) { src = wk; dst = wkb; off = i - 2097152; }
        else                  { src = wv; dst = wvb; off = i - 2359296; }
        float4 v = reinterpret_cast<const float4*>(src)[off];
        union { bf16 b[4]; ushort4 u; } t;
        t.b[0] = (bf16)v.x; t.b[1] = (bf16)v.y;
        t.b[2] = (bf16)v.z; t.b[3] = (bf16)v.w;
        reinterpret_cast<ushort4*>(dst)[off] = t.u;
    }
}

// ====== 64x128 tile, BK=64, dbuf GEMM body (16 MFMA/wave per barrier) =======
// (r1-proven; used by gemm_out only)
#define GEMM_BODY()                                                            \
    __shared__ __align__(16) bf16 smem[2 * (64 + 128) * 64]; /* 48 KB */       \
    int tid = threadIdx.x;                                                     \
    int lane = tid & 63, wid = tid >> 6;                                       \
    int l15 = lane & 15, quad = lane >> 4;                                     \
    int rlocal = lane >> 3;                                                    \
    int scol = ((lane & 7) ^ rlocal) * 8;                                      \
    const bf16* gA = A + (size_t)(m0 + wid * 16 + rlocal) * K + scol;          \
    const bf16* gB = B + (size_t)(n0 + wid * 32 + rlocal) * K + scol;          \
    int ldsOfA = (wid * 16) * 64;                                               \
    int ldsOfB = (wid * 32) * 64;                                               \
    floatx4 acc[2][4];                                                         \
    _Pragma("unroll") for (int mi = 0; mi < 2; ++mi)                           \
        _Pragma("unroll") for (int ni = 0; ni < 4; ++ni)                       \
            acc[mi][ni] = floatx4{0.f, 0.f, 0.f, 0.f};                         \
    int mb = (wid & 1) * 32, nb = (wid >> 1) * 64;                             \
    _Pragma("unroll") for (int j = 0; j < 2; ++j)                              \
        async16(gA + (size_t)(j * 8) * K, smem + ldsOfA + j * 512);            \
    _Pragma("unroll") for (int j = 0; j < 4; ++j)                              \
        async16(gB + (size_t)(j * 8) * K, smem + 8192 + ldsOfB + j * 512);     \
    int buf = 0;                                                               \
    for (int k0 = 0; k0 < K; k0 += 64) {                                       \
        __syncthreads();                                                       \
        if (k0 + 64 < K) {                                                     \
            int nof = buf ^ 1;                                                 \
            _Pragma("unroll") for (int j = 0; j < 2; ++j)                      \
                async16(gA + (size_t)(j * 8) * K + k0 + 64,                    \
                        smem + nof * 4096 + ldsOfA + j * 512);                 \
            _Pragma("unroll") for (int j = 0; j < 4; ++j)                      \
                async16(gB + (size_t)(j * 8) * K + k0 + 64,                    \
                        smem + 8192 + nof * 8192 + ldsOfB + j * 512);          \
        }                                                                      \
        const bf16* sA = smem + buf * 4096;                                    \
        const bf16* sB = smem + 8192 + buf * 8192;                             \
        _Pragma("unroll") for (int kc = 0; kc < 2; ++kc) {                     \
            bf16x8 af[2], bq[4];                                               \
            int ch = ((kc << 2) + quad) ^ (l15 & 7);                           \
            _Pragma("unroll") for (int i = 0; i < 2; ++i)                      \
                af[i] = load_bf8(sA + (mb + i * 16 + l15) * 64 + ch * 8);      \
            _Pragma("unroll") for (int i = 0; i < 4; ++i)                      \
                bq[i] = load_bf8(sB + (nb + i * 16 + l15) * 64 + ch * 8);      \
            _Pragma("unroll") for (int mi = 0; mi < 2; ++mi)                   \
                _Pragma("unroll") for (int ni = 0; ni < 4; ++ni)               \
                    acc[mi][ni] = __builtin_amdgcn_mfma_f32_16x16x32_bf16(     \
                        af[mi], bq[ni], acc[mi][ni], 0, 0, 0);                 \
        }                                                                      \
        buf ^= 1;                                                              \
    }

// ====== QKV GEMM, FAT-WAVE: BM=128, BN=256, BK=64, 4 waves (r3, FROZEN) =====
// Pinned at ~47us across 6 schedule/occupancy/placement variants (r0-r6) =
// issue-port floor at the measured ~1.05GHz effective clock (553 TF = 51% of
// clock-derated MFMA ceiling). Do not touch.
__global__ __launch_bounds__(256, 1) void gemm_qkv_fused(
    const bf16* __restrict__ A, const bf16* __restrict__ B,
    const float* __restrict__ qw, const float* __restrict__ kw,
    bf16* __restrict__ qb, bf16* __restrict__ kb, bf16* __restrict__ vtb) {
    const int K = 2048;
    int m0 = blockIdx.y * 128, n0 = blockIdx.x * 256;
    __shared__ __align__(16) bf16 smem[2 * 24576];  // 2 x (A 16KB + B 32KB)
    int tid = threadIdx.x;
    int lane = tid & 63, wid = tid >> 6;
    int l15 = lane & 15, quad = lane >> 4;
    int rlocal = lane >> 3;
    int scol = ((lane & 7) ^ rlocal) * 8;
    const bf16* gA = A + (size_t)(m0 + wid * 32 + rlocal) * K + scol;
    const bf16* gB = B + (size_t)(n0 + wid * 64 + rlocal) * K + scol;
    int mb = (wid & 1) * 64, nb = (wid >> 1) * 128;

    floatx4 acc[4][8];
#pragma unroll
    for (int mi = 0; mi < 4; ++mi)
#pragma unroll
        for (int ni = 0; ni < 8; ++ni) acc[mi][ni] = floatx4{0.f, 0.f, 0.f, 0.f};

    // prologue: stage k-tile 0 into buf 0 (A: 4, B: 8 async16 per wave)
#pragma unroll
    for (int j = 0; j < 4; ++j)
        async16(gA + (size_t)(j * 8) * K, smem + (wid * 32 + j * 8) * 64);
#pragma unroll
    for (int j = 0; j < 8; ++j)
        async16(gB + (size_t)(j * 8) * K, smem + 8192 + (wid * 64 + j * 8) * 64);

    int buf = 0;
    for (int k0 = 0; k0 < K; k0 += 64) {
        __syncthreads();
        if (k0 + 64 < K) {
            bf16* nbase = smem + (buf ^ 1) * 24576;
#pragma unroll
            for (int j = 0; j < 4; ++j)
                async16(gA + (size_t)(j * 8) * K + k0 + 64,
                        nbase + (wid * 32 + j * 8) * 64);
#pragma unroll
            for (int j = 0; j < 8; ++j)
                async16(gB + (size_t)(j * 8) * K + k0 + 64,
                        nbase + 8192 + (wid * 64 + j * 8) * 64);
        }
        const bf16* sA = smem + buf * 24576;
        const bf16* sB = sA + 8192;
#pragma unroll
        for (int kc = 0; kc < 2; ++kc) {
            bf16x8 af[4], bq[8];
            int ch = ((kc << 2) + quad) ^ (l15 & 7);
#pragma unroll
            for (int i = 0; i < 4; ++i)
                af[i] = load_bf8(sA + (mb + i * 16 + l15) * 64 + ch * 8);
#pragma unroll
            for (int n = 0; n < 8; ++n)
                bq[n] = load_bf8(sB + (nb + n * 16 + l15) * 64 + ch * 8);
#pragma unroll
            for (int mi = 0; mi < 4; ++mi)
#pragma unroll
                for (int ni = 0; ni < 8; ++ni)
                    acc[mi][ni] = __builtin_amdgcn_mfma_f32_16x16x32_bf16(
                        af[mi], bq[ni], acc[mi][ni], 0, 0, 0);
        }
        buf ^= 1;
    }

    // ---- clip ----
#pragma unroll
    for (int mi = 0; mi < 4; ++mi)
#pragma unroll
        for (int ni = 0; ni < 8; ++ni)
#pragma unroll
            for (int r = 0; r < 4; ++r)
                acc[mi][ni][r] = fminf(fmaxf(acc[mi][ni][r], -8.0f), 8.0f);

    if (n0 >= 2560) {  // V: transpose-store, no norm/rope (block x=10,11)
#pragma unroll
        for (int mi = 0; mi < 4; ++mi)
#pragma unroll
            for (int ni = 0; ni < 8; ++ni)
#pragma unroll
                for (int r = 0; r < 4; ++r) {
                    int row = m0 + mb + mi * 16 + quad * 4 + r;
                    int n = n0 + nb + ni * 16 + l15;
                    vtb[(size_t)(n - 2560) * 2048 + row] = (bf16)acc[mi][ni][r];
                }
        return;
    }

    // ---- RMSNorm, fully in-register (wave owns all 128 cols of its head) ---
    const float* nw = (n0 < 2048) ? qw : kw;
    float nwv[8];
#pragma unroll
    for (int ni = 0; ni < 8; ++ni) nwv[ni] = nw[(nb + ni * 16 + l15) & 127];
#pragma unroll
    for (int mi = 0; mi < 4; ++mi)
#pragma unroll
        for (int r = 0; r < 4; ++r) {
            float s = 0.f;
#pragma unroll
            for (int ni = 0; ni < 8; ++ni) s += acc[mi][ni][r] * acc[mi][ni][r];
#pragma unroll
            for (int o = 1; o < 16; o <<= 1) s += __shfl_xor(s, o, 64);
            float rinv = rsqrtf(s * (1.0f / 128.0f) + 1e-6f);
#pragma unroll
            for (int ni = 0; ni < 8; ++ni) acc[mi][ni][r] *= rinv * nwv[ni];
        }

    // ---- RoPE (partner col^64 == ni^4, in-register; same angle) + store ----
    float invf[4];
#pragma unroll
    for (int ni = 0; ni < 4; ++ni) {
        int fi = ni * 16 + l15;  // (nb + ni*16 + l15) & 63, nb in {0,128}
        invf[ni] = __expf((float)fi * (-13.122363377404328f / 64.0f));
    }
#pragma unroll
    for (int mi = 0; mi < 4; ++mi)
#pragma unroll
        for (int r = 0; r < 4; ++r) {
            int row = mb + mi * 16 + quad * 4 + r;
            int s = m0 + row;
            float pos = (float)s;
#pragma unroll
            for (int ni = 0; ni < 4; ++ni) {
                float ang = pos * invf[ni];
                float c = __cosf(ang), sn = __sinf(ang);
                float a = acc[mi][ni][r], b2 = acc[mi][ni + 4][r];
                float olo = a * c - b2 * sn;
                float ohi = b2 * c + a * sn;
                int nlo = n0 + nb + ni * 16 + l15;
                if (n0 < 2048) {
                    qb[(size_t)s * 2048 + nlo] = (bf16)olo;
                    qb[(size_t)s * 2048 + nlo + 64] = (bf16)ohi;
                } else {
                    kb[(size_t)s * 512 + (nlo - 2048)] = (bf16)olo;
                    kb[(size_t)s * 512 + (nlo - 2048) + 64] = (bf16)ohi;
                }
            }
        }
}

// ---------- out-proj GEMM: 64x128 tile, BK=64, dbuf (fp32 out, r3) ---------
__global__ __launch_bounds__(256) void gemm_out(
    const bf16* __restrict__ A, const bf16* __restrict__ B,
    float* __restrict__ C) {
    const int K = 2048, N = 2048;
    int m0 = blockIdx.y * 64, n0 = blockIdx.x * 128;
    GEMM_BODY()
#pragma unroll
    for (int mi = 0; mi < 2; ++mi)
#pragma unroll
        for (int ni = 0; ni < 4; ++ni)
#pragma unroll
            for (int r = 0; r < 4; ++r) {
                int m = m0 + mb + mi * 16 + quad * 4 + r;
                int n = n0 + nb + ni * 16 + l15;
                C[(size_t)m * N + n] = acc[mi][ni][r];
            }
}

// -------- flash attention (r3 structure) + wo-convert + full-tile fast path -
// wo conversion rides here: it's independent of attn, only gemm_out (later on
// the stream) consumes wob -> its 25MB of traffic overlaps attn's compute.
// Full tiles (bq0-960 <= t <= bq0-64; 15 of ~17 per block) skip the per-
// element causal/window test -- wave-uniform branch, identical numerics.
__global__ __launch_bounds__(256) void attn(
    const bf16* __restrict__ qb, const bf16* __restrict__ kb,
    const bf16* __restrict__ vtb, const float* __restrict__ sinks,
    const float* __restrict__ wo, bf16* __restrict__ wob,
    bf16* __restrict__ attb) {
    __shared__ __align__(16) bf16 sK[2][64 * 128];   // 32 KB, swizzled
    __shared__ __align__(16) bf16 sV[2][128 * 64];   // 32 KB, swizzled
    __shared__ __align__(16) bf16 sP[64 * 72];       // 9 KB shared P, padded
    __shared__ float redu[64][4];                    // row-sum partials
    int tid = threadIdx.x;
    int lane = tid & 63, wid = tid >> 6;
    int l15 = lane & 15, quad = lane >> 4;
    int h = blockIdx.y, kh = h >> 2;
    int bq0 = blockIdx.x * 64;

    // ---- wo-convert prologue (512 blocks x 256 thr; 8 float4 each) ----
    {
        int bindex = blockIdx.y * gridDim.x + blockIdx.x;   // 0..511
        for (int i = bindex * 256 + tid; i < 1048576; i += 512 * 256) {
            float4 v = reinterpret_cast<const float4*>(wo)[i];
            union { bf16 b[4]; ushort4 u; } t2;
            t2.b[0] = (bf16)v.x; t2.b[1] = (bf16)v.y;
            t2.b[2] = (bf16)v.z; t2.b[3] = (bf16)v.w;
            reinterpret_cast<ushort4*>(wob)[i] = t2.u;
        }
    }

    // Q stationary: all 64 queries of this block, head h. frag[n=l15][k=quad*8+j]
    bf16x8 qf[4][4];
#pragma unroll
    for (int ni = 0; ni < 4; ++ni) {
        const bf16* qrow = qb + (size_t)(bq0 + ni * 16 + l15) * 2048 + h * 128 + quad * 8;
#pragma unroll
        for (int kc = 0; kc < 4; ++kc) qf[ni][kc] = load_bf8(qrow + kc * 32);
    }

    floatx4 acc[4][2];  // [mi][df]: 64 q x this wave's 32 dims
#pragma unroll
    for (int mi = 0; mi < 4; ++mi)
#pragma unroll
        for (int df = 0; df < 2; ++df) acc[mi][df] = floatx4{0.f, 0.f, 0.f, 0.f};
    float lpq[4];       // per-lane partial row sums (keys quad*4..+4 of wave)
#pragma unroll
    for (int ni = 0; ni < 4; ++ni) lpq[ni] = 0.f;

    // staging (XOR chunk swizzles; LDS dest forced = lane*16)
    int keyit = wid * 4 + (lane >> 4);
    int gcK = (lane & 15) ^ keyit;
    int dimit = wid * 8 + (lane >> 3);
    int gcV = (lane & 7) ^ ((lane >> 3) & 7);

    int tstart = bq0 - 1024; if (tstart < 0) tstart = 0;
    const bf16* kbase = kb + (size_t)kh * 128;
    const bf16* vbase = vtb + (size_t)kh * 128 * 2048;

#pragma unroll
    for (int r = 0; r < 4; ++r) {
        async16(kbase + (size_t)(tstart + r * 16 + keyit) * 512 + gcK * 8,
                sK[0] + (r * 16 + wid * 4) * 128);
        async16(vbase + (size_t)(r * 32 + dimit) * 2048 + tstart + gcV * 8,
                sV[0] + (r * 32 + wid * 8) * 64);
    }

    int buf = 0;
    for (int t = tstart; t <= bq0; t += 64) {
        __syncthreads();   // tile(buf) ready; sP from last iter fully consumed
        if (t + 64 <= bq0) {
#pragma unroll
            for (int r = 0; r < 4; ++r) {
                async16(kbase + (size_t)(t + 64 + r * 16 + keyit) * 512 + gcK * 8,
                        sK[buf ^ 1] + (r * 16 + wid * 4) * 128);
                async16(vbase + (size_t)(r * 32 + dimit) * 2048 + t + 64 + gcV * 8,
                        sV[buf ^ 1] + (r * 32 + wid * 8) * 64);
            }
        }
        // ---- phase 1: S^T = K·Q^T for this wave's 16 keys ----
        floatx4 ST[4];
#pragma unroll
        for (int ni = 0; ni < 4; ++ni) ST[ni] = floatx4{0.f, 0.f, 0.f, 0.f};
#pragma unroll
        for (int kc = 0; kc < 4; ++kc) {
            int ch = (kc * 4 + quad) ^ l15;  // row&15 == l15
            bf16x8 kf = load_bf8(sK[buf] + (wid * 16 + l15) * 128 + ch * 8);
#pragma unroll
            for (int ni = 0; ni < 4; ++ni)
                ST[ni] = __builtin_amdgcn_mfma_f32_16x16x32_bf16(kf, qf[ni][kc], ST[ni], 0, 0, 0);
        }
        int kbi = t + wid * 16 + quad * 4;  // this lane's first key
        // full tile: every (q,k) in this tile passes causal+window for all
        // 64 queries of the block -> skip the mask (wave-uniform branch)
        bool fullt = (t <= bq0 - 64) && (t >= bq0 - 960);
        if (fullt) {
#pragma unroll
            for (int ni = 0; ni < 4; ++ni) {
                bf16x4 pv;
#pragma unroll
                for (int r = 0; r < 4; ++r) {
                    float e = __expf(ST[ni][r] * 0.08838834764831845f);
                    lpq[ni] += e;
                    pv[r] = (bf16)e;
                }
                *(bf16x4*)(sP + (ni * 16 + l15) * 72 + wid * 16 + quad * 4) = pv;
            }
        } else {
#pragma unroll
            for (int ni = 0; ni < 4; ++ni) {
                int qi = bq0 + ni * 16 + l15;
                bf16x4 pv;
#pragma unroll
                for (int r = 0; r < 4; ++r) {
                    int ki = kbi + r;
                    float v = ST[ni][r] * 0.08838834764831845f;  // 1/sqrt(128)
                    bool ok = (ki <= qi) && (ki > qi - WINDOW);
                    float e = ok ? __expf(v) : 0.0f;
                    lpq[ni] += e;
                    pv[r] = (bf16)e;
                }
                *(bf16x4*)(sP + (ni * 16 + l15) * 72 + wid * 16 + quad * 4) = pv;
            }
        }
        __syncthreads();   // P complete
        // ---- phase 2: PV for this wave's 32 dims ----
#pragma unroll
        for (int kc = 0; kc < 2; ++kc) {
            bf16x8 pf[4];
#pragma unroll
            for (int mi = 0; mi < 4; ++mi)
                pf[mi] = load_bf8(sP + (mi * 16 + l15) * 72 + kc * 32 + quad * 8);
#pragma unroll
            for (int df = 0; df < 2; ++df) {
                int dim = wid * 32 + df * 16 + l15;
                int ch = (kc * 4 + quad) ^ (l15 & 7);
                bf16x8 vf = load_bf8(sV[buf] + dim * 64 + ch * 8);
#pragma unroll
                for (int mi = 0; mi < 4; ++mi)
                    acc[mi][df] = __builtin_amdgcn_mfma_f32_16x16x32_bf16(pf[mi], vf, acc[mi][df], 0, 0, 0);
            }
        }
        buf ^= 1;
    }

    // reduce lpq over the 4 key-subgroups (quad) of this wave, then cross-wave
#pragma unroll
    for (int ni = 0; ni < 4; ++ni) {
        float v = lpq[ni];
        v += __shfl_xor(v, 16, 64);
        v += __shfl_xor(v, 32, 64);
        if (quad == 0) redu[ni * 16 + l15][wid] = v;
    }
    __syncthreads();
    float sk = __expf(sinks[h]);
#pragma unroll
    for (int mi = 0; mi < 4; ++mi)
#pragma unroll
        for (int r = 0; r < 4; ++r) {
            int row = mi * 16 + quad * 4 + r;
            float rs = redu[row][0] + redu[row][1] + redu[row][2] + redu[row][3] + sk;
            float inv = 1.0f / rs;
#pragma unroll
            for (int df = 0; df < 2; ++df) {
                int dim = wid * 32 + df * 16 + l15;
                attb[(size_t)(bq0 + row) * 2048 + h * 128 + dim] =
                    (bf16)(acc[mi][df][r] * inv);
            }
        }
}

extern "C" void kernel_launch(void* const* d_in, const int* in_sizes, int n_in,
                              void* d_out, int out_size, void* d_ws, size_t ws_size,
                              hipStream_t stream) {
    const float* x      = (const float*)d_in[0];
    const float* w_q    = (const float*)d_in[1];
    const float* w_k    = (const float*)d_in[2];
    const float* w_v    = (const float*)d_in[3];
    const float* w_out  = (const float*)d_in[4];
    const float* q_norm = (const float*)d_in[5];
    const float* k_norm = (const float*)d_in[6];
    const float* sinks  = (const float*)d_in[7];

    char* ws = (char*)d_ws;
    const size_t MB = 1u << 20;
    bf16* xb   = (bf16*)(ws + 0 * MB);    // 8 MB
    bf16* wqb  = (bf16*)(ws + 8 * MB);    // 8 MB  (wqb/wkb/wvb contiguous)
    bf16* wkb  = (bf16*)(ws + 16 * MB);   // 2 MB  (forms wcomb [3072][2048])
    bf16* wvb  = (bf16*)(ws + 18 * MB);   // 2 MB
    bf16* wob  = (bf16*)(ws + 20 * MB);   // 8 MB
    bf16* qb   = (bf16*)(ws + 28 * MB);   // 8 MB  (post norm+rope)
    bf16* kb   = (bf16*)(ws + 36 * MB);   // 2 MB
    bf16* vtb  = (bf16*)(ws + 38 * MB);   // 2 MB  (V transposed)
    bf16* attb = (bf16*)(ws + 40 * MB);   // 8 MB
    bf16* wcomb = wqb;                    // rows 0..3071 = [w_q; w_k; w_v]
    float* out = (float*)d_out;

    convert_kernel<<<2048, 256, 0, stream>>>(x, w_q, w_k, w_v,
                                             xb, wqb, wkb, wvb);
    gemm_qkv_fused<<<dim3(12, 16), 256, 0, stream>>>(xb, wcomb, q_norm, k_norm,
                                                     qb, kb, vtb);
    attn<<<dim3(32, 16), 256, 0, stream>>>(qb, kb, vtb, sinks, w_out, wob, attb);
    gemm_out<<<dim3(16, 32), 256, 0, stream>>>(attb, wob, out);
}

// Round 11
// 199.550 us; speedup vs baseline: 1.9380x; 1.0035x over previous
//
#include <hip/hip_runtime.h>
#include <hip/hip_bf16.h>
#include <math.h>

#define S_LEN 2048
#define DMODEL 2048
#define NH 16
#define NKVH 4
#define HDIM 128
#define WINDOW 1024

typedef __bf16 bf16;
typedef __bf16 bf16x8 __attribute__((ext_vector_type(8)));
typedef __bf16 bf16x4 __attribute__((ext_vector_type(4)));
typedef float floatx4 __attribute__((ext_vector_type(4)));
typedef float floatx16 __attribute__((ext_vector_type(16)));

static __device__ __forceinline__ bf16x8 load_bf8(const bf16* p) {
    return *reinterpret_cast<const bf16x8*>(p);
}

// async 16B global->LDS (wave-uniform LDS base + lane*16)
static __device__ __forceinline__ void async16(const bf16* g, bf16* l) {
    __builtin_amdgcn_global_load_lds(
        (const __attribute__((address_space(1))) void*)g,
        (__attribute__((address_space(3))) void*)l, 16, 0, 0);
}

// -------- fp32 -> bf16 conversion of x and QKV weights (wo rides in attn) ---
__global__ __launch_bounds__(256) void convert_kernel(
    const float* __restrict__ x, const float* __restrict__ wq,
    const float* __restrict__ wk, const float* __restrict__ wv,
    bf16* __restrict__ xb, bf16* __restrict__ wqb, bf16* __restrict__ wkb,
    bf16* __restrict__ wvb) {
    for (int i = blockIdx.x * blockDim.x + threadIdx.x; i < 2621440;
         i += gridDim.x * blockDim.x) {
        const float* src; bf16* dst; int off;
        if      (i < 1048576) { src = x;  dst = xb;  off = i; }
        else if (i < 2097152) { src = wq; dst = wqb; off = i - 1048576; }
        else if (i < 2359296) { src = wk; dst = wkb; off = i - 2097152; }
        else                  { src = wv; dst = wvb; off = i - 2359296; }
        float4 v = reinterpret_cast<const float4*>(src)[off];
        union { bf16 b[4]; ushort4 u; } t;
        t.b[0] = (bf16)v.x; t.b[1] = (bf16)v.y;
        t.b[2] = (bf16)v.z; t.b[3] = (bf16)v.w;
        reinterpret_cast<ushort4*>(dst)[off] = t.u;
    }
}

// ====== 64x128 tile, BK=64, dbuf GEMM body (r1-proven; gemm_out only) =======
#define GEMM_BODY()                                                            \
    __shared__ __align__(16) bf16 smem[2 * (64 + 128) * 64]; /* 48 KB */       \
    int tid = threadIdx.x;                                                     \
    int lane = tid & 63, wid = tid >> 6;                                       \
    int l15 = lane & 15, quad = lane >> 4;                                     \
    int rlocal = lane >> 3;                                                    \
    int scol = ((lane & 7) ^ rlocal) * 8;                                      \
    const bf16* gA = A + (size_t)(m0 + wid * 16 + rlocal) * K + scol;          \
    const bf16* gB = B + (size_t)(n0 + wid * 32 + rlocal) * K + scol;          \
    int ldsOfA = (wid * 16) * 64;                                               \
    int ldsOfB = (wid * 32) * 64;                                               \
    floatx4 acc[2][4];                                                         \
    _Pragma("unroll") for (int mi = 0; mi < 2; ++mi)                           \
        _Pragma("unroll") for (int ni = 0; ni < 4; ++ni)                       \
            acc[mi][ni] = floatx4{0.f, 0.f, 0.f, 0.f};                         \
    int mb = (wid & 1) * 32, nb = (wid >> 1) * 64;                             \
    _Pragma("unroll") for (int j = 0; j < 2; ++j)                              \
        async16(gA + (size_t)(j * 8) * K, smem + ldsOfA + j * 512);            \
    _Pragma("unroll") for (int j = 0; j < 4; ++j)                              \
        async16(gB + (size_t)(j * 8) * K, smem + 8192 + ldsOfB + j * 512);     \
    int buf = 0;                                                               \
    for (int k0 = 0; k0 < K; k0 += 64) {                                       \
        __syncthreads();                                                       \
        if (k0 + 64 < K) {                                                     \
            int nof = buf ^ 1;                                                 \
            _Pragma("unroll") for (int j = 0; j < 2; ++j)                      \
                async16(gA + (size_t)(j * 8) * K + k0 + 64,                    \
                        smem + nof * 4096 + ldsOfA + j * 512);                 \
            _Pragma("unroll") for (int j = 0; j < 4; ++j)                      \
                async16(gB + (size_t)(j * 8) * K + k0 + 64,                    \
                        smem + 8192 + nof * 8192 + ldsOfB + j * 512);          \
        }                                                                      \
        const bf16* sA = smem + buf * 4096;                                    \
        const bf16* sB = smem + 8192 + buf * 8192;                             \
        _Pragma("unroll") for (int kc = 0; kc < 2; ++kc) {                     \
            bf16x8 af[2], bq[4];                                               \
            int ch = ((kc << 2) + quad) ^ (l15 & 7);                           \
            _Pragma("unroll") for (int i = 0; i < 2; ++i)                      \
                af[i] = load_bf8(sA + (mb + i * 16 + l15) * 64 + ch * 8);      \
            _Pragma("unroll") for (int i = 0; i < 4; ++i)                      \
                bq[i] = load_bf8(sB + (nb + i * 16 + l15) * 64 + ch * 8);      \
            _Pragma("unroll") for (int mi = 0; mi < 2; ++mi)                   \
                _Pragma("unroll") for (int ni = 0; ni < 4; ++ni)               \
                    acc[mi][ni] = __builtin_amdgcn_mfma_f32_16x16x32_bf16(     \
                        af[mi], bq[ni], acc[mi][ni], 0, 0, 0);                 \
        }                                                                      \
        buf ^= 1;                                                              \
    }

// ====== QKV GEMM, fat-wave, 32x32x16 MFMA: BM=128, BN=256, BK=64 ===========
// r11 change: 16x16x32 -> 32x32x16 halves MFMA instruction count (64->32 per
// wave-step, same FLOPs; matrix-busy 310->~256 cyc/step per m119 rates).
// Tests whether the pinned ~48us is issue/pipe-bound (gain) vs pure-latency
// (null). Staging swizzle gains a ^(j&3) term so the 32-row column read stays
// 2-way per 16-lane phase (conflict-free class; watch SQ_LDS_BANK_CONFLICT).
// C-layout (m74/m101): col=lane&31, row=(reg&3)+8*(reg>>2)+4*(lane>>5).
__global__ __launch_bounds__(256, 1) void gemm_qkv_fused(
    const bf16* __restrict__ A, const bf16* __restrict__ B,
    const float* __restrict__ qw, const float* __restrict__ kw,
    bf16* __restrict__ qb, bf16* __restrict__ kb, bf16* __restrict__ vtb) {
    const int K = 2048;
    int m0 = blockIdx.y * 128, n0 = blockIdx.x * 256;
    __shared__ __align__(16) bf16 smem[2 * 24576];  // 2 x (A 16KB + B 32KB)
    int tid = threadIdx.x;
    int lane = tid & 63, wid = tid >> 6;
    int l31 = lane & 31, half = lane >> 5;
    int rlocal = lane >> 3;                          // row&7 of staged row
    const bf16* gAr = A + (size_t)(m0 + wid * 32 + rlocal) * K;
    const bf16* gBr = B + (size_t)(n0 + wid * 64 + rlocal) * K;
    int mb = (wid & 1) * 64, nb = (wid >> 1) * 128;

    floatx16 acc[2][4];
#pragma unroll
    for (int rt = 0; rt < 2; ++rt)
#pragma unroll
        for (int ct = 0; ct < 4; ++ct)
#pragma unroll
            for (int e = 0; e < 16; ++e) acc[rt][ct][e] = 0.f;

    // staging: LDS[row][p] = global chunk p ^ (row&7) ^ ((row>>3)&3)
    // (j&3 == (row>>3)&3 within the wave's region since wid*32/wid*64 are
    //  multiples of 32 -> their >>3 is a multiple of 4)
#pragma unroll
    for (int j = 0; j < 4; ++j)
        async16(gAr + (size_t)(j * 8) * K + (((lane & 7) ^ rlocal ^ (j & 3)) * 8),
                smem + (wid * 32 + j * 8) * 64);
#pragma unroll
    for (int j = 0; j < 8; ++j)
        async16(gBr + (size_t)(j * 8) * K + (((lane & 7) ^ rlocal ^ (j & 3)) * 8),
                smem + 8192 + (wid * 64 + j * 8) * 64);

    int buf = 0;
    for (int k0 = 0; k0 < K; k0 += 64) {
        __syncthreads();
        if (k0 + 64 < K) {
            bf16* nbase = smem + (buf ^ 1) * 24576;
#pragma unroll
            for (int j = 0; j < 4; ++j)
                async16(gAr + (size_t)(j * 8) * K + k0 + 64 +
                            (((lane & 7) ^ rlocal ^ (j & 3)) * 8),
                        nbase + (wid * 32 + j * 8) * 64);
#pragma unroll
            for (int j = 0; j < 8; ++j)
                async16(gBr + (size_t)(j * 8) * K + k0 + 64 +
                            (((lane & 7) ^ rlocal ^ (j & 3)) * 8),
                        nbase + 8192 + (wid * 64 + j * 8) * 64);
        }
        const bf16* sA = smem + buf * 24576;
        const bf16* sB = sA + 8192;
#pragma unroll
        for (int kc = 0; kc < 4; ++kc) {    // 4 k-chunks of 16
            // global chunk c = kc*2 + half; LDS pos = c ^ (row&7) ^ ((row>>3)&3)
            int ch = ((kc << 1) + half) ^ (lane & 7) ^ ((l31 >> 3) & 3);
            bf16x8 af[2], bq[4];
#pragma unroll
            for (int rt = 0; rt < 2; ++rt)
                af[rt] = load_bf8(sA + (mb + rt * 32 + l31) * 64 + ch * 8);
#pragma unroll
            for (int ct = 0; ct < 4; ++ct)
                bq[ct] = load_bf8(sB + (nb + ct * 32 + l31) * 64 + ch * 8);
#pragma unroll
            for (int rt = 0; rt < 2; ++rt)
#pragma unroll
                for (int ct = 0; ct < 4; ++ct)
                    acc[rt][ct] = __builtin_amdgcn_mfma_f32_32x32x16_bf16(
                        af[rt], bq[ct], acc[rt][ct], 0, 0, 0);
        }
        buf ^= 1;
    }

    // ---- clip ----
#pragma unroll
    for (int rt = 0; rt < 2; ++rt)
#pragma unroll
        for (int ct = 0; ct < 4; ++ct)
#pragma unroll
            for (int e = 0; e < 16; ++e)
                acc[rt][ct][e] = fminf(fmaxf(acc[rt][ct][e], -8.0f), 8.0f);

    // C mapping: ncol = nb + ct*32 + l31; mrow = mb + rt*32 + rfun(e,half)
    // rfun = (e&3) + 8*(e>>2) + 4*half
    if (n0 >= 2560) {  // V: transpose-store, no norm/rope
#pragma unroll
        for (int rt = 0; rt < 2; ++rt)
#pragma unroll
            for (int ct = 0; ct < 4; ++ct)
#pragma unroll
                for (int e = 0; e < 16; ++e) {
                    int row = m0 + mb + rt * 32 + (e & 3) + 8 * (e >> 2) + 4 * half;
                    int n = n0 + nb + ct * 32 + l31;
                    vtb[(size_t)(n - 2560) * 2048 + row] = (bf16)acc[rt][ct][e];
                }
        return;
    }

    // ---- RMSNorm, in-register; row spans 4 ct-tiles x 32 lanes (same half) -
    const float* nw = (n0 < 2048) ? qw : kw;
    float nwv[4];
#pragma unroll
    for (int ct = 0; ct < 4; ++ct) nwv[ct] = nw[(nb + ct * 32 + l31) & 127];
#pragma unroll
    for (int rt = 0; rt < 2; ++rt)
#pragma unroll
        for (int e = 0; e < 16; ++e) {
            float s = acc[rt][0][e] * acc[rt][0][e] + acc[rt][1][e] * acc[rt][1][e]
                    + acc[rt][2][e] * acc[rt][2][e] + acc[rt][3][e] * acc[rt][3][e];
#pragma unroll
            for (int o = 1; o < 32; o <<= 1) s += __shfl_xor(s, o, 64);
            float rinv = rsqrtf(s * (1.0f / 128.0f) + 1e-6f);
#pragma unroll
            for (int ct = 0; ct < 4; ++ct) acc[rt][ct][e] *= rinv * nwv[ct];
        }

    // ---- RoPE (partner col^64 == ct^2, in-register; same angle) + store ----
    float invf[2];
#pragma unroll
    for (int ct = 0; ct < 2; ++ct) {
        int fi = ct * 32 + l31;   // (nb + ct*32 + l31) & 63, nb in {0,128}
        invf[ct] = __expf((float)fi * (-13.122363377404328f / 64.0f));
    }
#pragma unroll
    for (int rt = 0; rt < 2; ++rt)
#pragma unroll
        for (int e = 0; e < 16; ++e) {
            int row = mb + rt * 32 + (e & 3) + 8 * (e >> 2) + 4 * half;
            int s = m0 + row;
            float pos = (float)s;
#pragma unroll
            for (int ct = 0; ct < 2; ++ct) {
                float ang = pos * invf[ct];
                float c = __cosf(ang), sn = __sinf(ang);
                float a = acc[rt][ct][e], b2 = acc[rt][ct + 2][e];
                float olo = a * c - b2 * sn;
                float ohi = b2 * c + a * sn;
                int nlo = n0 + nb + ct * 32 + l31;
                if (n0 < 2048) {
                    qb[(size_t)s * 2048 + nlo] = (bf16)olo;
                    qb[(size_t)s * 2048 + nlo + 64] = (bf16)ohi;
                } else {
                    kb[(size_t)s * 512 + (nlo - 2048)] = (bf16)olo;
                    kb[(size_t)s * 512 + (nlo - 2048) + 64] = (bf16)ohi;
                }
            }
        }
}

// ---------- out-proj GEMM: 64x128 tile, BK=64, dbuf (fp32 out, r3) ---------
__global__ __launch_bounds__(256) void gemm_out(
    const bf16* __restrict__ A, const bf16* __restrict__ B,
    float* __restrict__ C) {
    const int K = 2048, N = 2048;
    int m0 = blockIdx.y * 64, n0 = blockIdx.x * 128;
    GEMM_BODY()
#pragma unroll
    for (int mi = 0; mi < 2; ++mi)
#pragma unroll
        for (int ni = 0; ni < 4; ++ni)
#pragma unroll
            for (int r = 0; r < 4; ++r) {
                int m = m0 + mb + mi * 16 + quad * 4 + r;
                int n = n0 + nb + ni * 16 + l15;
                C[(size_t)m * N + n] = acc[mi][ni][r];
            }
}

// -------- flash attention (r10: wo-convert ride + full-tile fast path) ------
__global__ __launch_bounds__(256) void attn(
    const bf16* __restrict__ qb, const bf16* __restrict__ kb,
    const bf16* __restrict__ vtb, const float* __restrict__ sinks,
    const float* __restrict__ wo, bf16* __restrict__ wob,
    bf16* __restrict__ attb) {
    __shared__ __align__(16) bf16 sK[2][64 * 128];   // 32 KB, swizzled
    __shared__ __align__(16) bf16 sV[2][128 * 64];   // 32 KB, swizzled
    __shared__ __align__(16) bf16 sP[64 * 72];       // 9 KB shared P, padded
    __shared__ float redu[64][4];                    // row-sum partials
    int tid = threadIdx.x;
    int lane = tid & 63, wid = tid >> 6;
    int l15 = lane & 15, quad = lane >> 4;
    int h = blockIdx.y, kh = h >> 2;
    int bq0 = blockIdx.x * 64;

    // ---- wo-convert prologue (512 blocks x 256 thr; 8 float4 each) ----
    {
        int bindex = blockIdx.y * gridDim.x + blockIdx.x;   // 0..511
        for (int i = bindex * 256 + tid; i < 1048576; i += 512 * 256) {
            float4 v = reinterpret_cast<const float4*>(wo)[i];
            union { bf16 b[4]; ushort4 u; } t2;
            t2.b[0] = (bf16)v.x; t2.b[1] = (bf16)v.y;
            t2.b[2] = (bf16)v.z; t2.b[3] = (bf16)v.w;
            reinterpret_cast<ushort4*>(wob)[i] = t2.u;
        }
    }

    // Q stationary: all 64 queries of this block, head h. frag[n=l15][k=quad*8+j]
    bf16x8 qf[4][4];
#pragma unroll
    for (int ni = 0; ni < 4; ++ni) {
        const bf16* qrow = qb + (size_t)(bq0 + ni * 16 + l15) * 2048 + h * 128 + quad * 8;
#pragma unroll
        for (int kc = 0; kc < 4; ++kc) qf[ni][kc] = load_bf8(qrow + kc * 32);
    }

    floatx4 acc[4][2];  // [mi][df]: 64 q x this wave's 32 dims
#pragma unroll
    for (int mi = 0; mi < 4; ++mi)
#pragma unroll
        for (int df = 0; df < 2; ++df) acc[mi][df] = floatx4{0.f, 0.f, 0.f, 0.f};
    float lpq[4];       // per-lane partial row sums (keys quad*4..+4 of wave)
#pragma unroll
    for (int ni = 0; ni < 4; ++ni) lpq[ni] = 0.f;

    // staging (XOR chunk swizzles; LDS dest forced = lane*16)
    int keyit = wid * 4 + (lane >> 4);
    int gcK = (lane & 15) ^ keyit;
    int dimit = wid * 8 + (lane >> 3);
    int gcV = (lane & 7) ^ ((lane >> 3) & 7);

    int tstart = bq0 - 1024; if (tstart < 0) tstart = 0;
    const bf16* kbase = kb + (size_t)kh * 128;
    const bf16* vbase = vtb + (size_t)kh * 128 * 2048;

#pragma unroll
    for (int r = 0; r < 4; ++r) {
        async16(kbase + (size_t)(tstart + r * 16 + keyit) * 512 + gcK * 8,
                sK[0] + (r * 16 + wid * 4) * 128);
        async16(vbase + (size_t)(r * 32 + dimit) * 2048 + tstart + gcV * 8,
                sV[0] + (r * 32 + wid * 8) * 64);
    }

    int buf = 0;
    for (int t = tstart; t <= bq0; t += 64) {
        __syncthreads();   // tile(buf) ready; sP from last iter fully consumed
        if (t + 64 <= bq0) {
#pragma unroll
            for (int r = 0; r < 4; ++r) {
                async16(kbase + (size_t)(t + 64 + r * 16 + keyit) * 512 + gcK * 8,
                        sK[buf ^ 1] + (r * 16 + wid * 4) * 128);
                async16(vbase + (size_t)(r * 32 + dimit) * 2048 + t + 64 + gcV * 8,
                        sV[buf ^ 1] + (r * 32 + wid * 8) * 64);
            }
        }
        // ---- phase 1: S^T = K·Q^T for this wave's 16 keys ----
        floatx4 ST[4];
#pragma unroll
        for (int ni = 0; ni < 4; ++ni) ST[ni] = floatx4{0.f, 0.f, 0.f, 0.f};
#pragma unroll
        for (int kc = 0; kc < 4; ++kc) {
            int ch = (kc * 4 + quad) ^ l15;  // row&15 == l15
            bf16x8 kf = load_bf8(sK[buf] + (wid * 16 + l15) * 128 + ch * 8);
#pragma unroll
            for (int ni = 0; ni < 4; ++ni)
                ST[ni] = __builtin_amdgcn_mfma_f32_16x16x32_bf16(kf, qf[ni][kc], ST[ni], 0, 0, 0);
        }
        int kbi = t + wid * 16 + quad * 4;  // this lane's first key
        // full tile: all (q,k) pass causal+window -> skip mask (wave-uniform)
        bool fullt = (t <= bq0 - 64) && (t >= bq0 - 960);
        if (fullt) {
#pragma unroll
            for (int ni = 0; ni < 4; ++ni) {
                bf16x4 pv;
#pragma unroll
                for (int r = 0; r < 4; ++r) {
                    float e = __expf(ST[ni][r] * 0.08838834764831845f);
                    lpq[ni] += e;
                    pv[r] = (bf16)e;
                }
                *(bf16x4*)(sP + (ni * 16 + l15) * 72 + wid * 16 + quad * 4) = pv;
            }
        } else {
#pragma unroll
            for (int ni = 0; ni < 4; ++ni) {
                int qi = bq0 + ni * 16 + l15;
                bf16x4 pv;
#pragma unroll
                for (int r = 0; r < 4; ++r) {
                    int ki = kbi + r;
                    float v = ST[ni][r] * 0.08838834764831845f;  // 1/sqrt(128)
                    bool ok = (ki <= qi) && (ki > qi - WINDOW);
                    float e = ok ? __expf(v) : 0.0f;
                    lpq[ni] += e;
                    pv[r] = (bf16)e;
                }
                *(bf16x4*)(sP + (ni * 16 + l15) * 72 + wid * 16 + quad * 4) = pv;
            }
        }
        __syncthreads();   // P complete
        // ---- phase 2: PV for this wave's 32 dims ----
#pragma unroll
        for (int kc = 0; kc < 2; ++kc) {
            bf16x8 pf[4];
#pragma unroll
            for (int mi = 0; mi < 4; ++mi)
                pf[mi] = load_bf8(sP + (mi * 16 + l15) * 72 + kc * 32 + quad * 8);
#pragma unroll
            for (int df = 0; df < 2; ++df) {
                int dim = wid * 32 + df * 16 + l15;
                int ch = (kc * 4 + quad) ^ (l15 & 7);
                bf16x8 vf = load_bf8(sV[buf] + dim * 64 + ch * 8);
#pragma unroll
                for (int mi = 0; mi < 4; ++mi)
                    acc[mi][df] = __builtin_amdgcn_mfma_f32_16x16x32_bf16(pf[mi], vf, acc[mi][df], 0, 0, 0);
            }
        }
        buf ^= 1;
    }

    // reduce lpq over the 4 key-subgroups (quad) of this wave, then cross-wave
#pragma unroll
    for (int ni = 0; ni < 4; ++ni) {
        float v = lpq[ni];
        v += __shfl_xor(v, 16, 64);
        v += __shfl_xor(v, 32, 64);
        if (quad == 0) redu[ni * 16 + l15][wid] = v;
    }
    __syncthreads();
    float sk = __expf(sinks[h]);
#pragma unroll
    for (int mi = 0; mi < 4; ++mi)
#pragma unroll
        for (int r = 0; r < 4; ++r) {
            int row = mi * 16 + quad * 4 + r;
            float rs = redu[row][0] + redu[row][1] + redu[row][2] + redu[row][3] + sk;
            float inv = 1.0f / rs;
#pragma unroll
            for (int df = 0; df < 2; ++df) {
                int dim = wid * 32 + df * 16 + l15;
                attb[(size_t)(bq0 + row) * 2048 + h * 128 + dim] =
                    (bf16)(acc[mi][df][r] * inv);
            }
        }
}

extern "C" void kernel_launch(void* const* d_in, const int* in_sizes, int n_in,
                              void* d_out, int out_size, void* d_ws, size_t ws_size,
                              hipStream_t stream) {
    const float* x      = (const float*)d_in[0];
    const float* w_q    = (const float*)d_in[1];
    const float* w_k    = (const float*)d_in[2];
    const float* w_v    = (const float*)d_in[3];
    const float* w_out  = (const float*)d_in[4];
    const float* q_norm = (const float*)d_in[5];
    const float* k_norm = (const float*)d_in[6];
    const float* sinks  = (const float*)d_in[7];

    char* ws = (char*)d_ws;
    const size_t MB = 1u << 20;
    bf16* xb   = (bf16*)(ws + 0 * MB);    // 8 MB
    bf16* wqb  = (bf16*)(ws + 8 * MB);    // 8 MB  (wqb/wkb/wvb contiguous)
    bf16* wkb  = (bf16*)(ws + 16 * MB);   // 2 MB  (forms wcomb [3072][2048])
    bf16* wvb  = (bf16*)(ws + 18 * MB);   // 2 MB
    bf16* wob  = (bf16*)(ws + 20 * MB);   // 8 MB
    bf16* qb   = (bf16*)(ws + 28 * MB);   // 8 MB  (post norm+rope)
    bf16* kb   = (bf16*)(ws + 36 * MB);   // 2 MB
    bf16* vtb  = (bf16*)(ws + 38 * MB);   // 2 MB  (V transposed)
    bf16* attb = (bf16*)(ws + 40 * MB);   // 8 MB
    bf16* wcomb = wqb;                    // rows 0..3071 = [w_q; w_k; w_v]
    float* out = (float*)d_out;

    convert_kernel<<<2048, 256, 0, stream>>>(x, w_q, w_k, w_v,
                                             xb, wqb, wkb, wvb);
    gemm_qkv_fused<<<dim3(12, 16), 256, 0, stream>>>(xb, wcomb, q_norm, k_norm,
                                                     qb, kb, vtb);
    attn<<<dim3(32, 16), 256, 0, stream>>>(qb, kb, vtb, sinks, w_out, wob, attb);
    gemm_out<<<dim3(16, 32), 256, 0, stream>>>(attb, wob, out);
}